// Round 16
// baseline (55.225 us; speedup 1.0000x reference)
//
#include <hip/hip_runtime.h>
#include <hip/hip_bf16.h>

// Sizes fixed by setup_inputs()
#define N_EL   1024
#define N_UP   512
#define NNUC   256
#define DIM    256
#define EDIM   32
#define KTOT   8192              // NNUC * EDIM, GEMM K dimension
#define NKP    16                // K-partitions (K=512 each)

#define GAIN_F      1.7872135f          // 1/std(silu(N(0,1))), analytic
#define INV_SQRT2_F 0.7071067811865476f

typedef __attribute__((ext_vector_type(8))) short bf16x8;
typedef __attribute__((ext_vector_type(4))) short bf16x4;
typedef __attribute__((ext_vector_type(4))) float f32x4;

__device__ __forceinline__ short f2bf(float x) {
    union { __hip_bfloat16 h; short s; } u;
    u.h = __float2bfloat16(x);     // compiler pk-fuses pairs (v_cvt_pk_bf16_f32)
    return u.s;
}

// ---------------------------------------------------------------------------
// K0 prep (R15 body, unchanged)
// ---------------------------------------------------------------------------
__global__ __launch_bounds__(256) void prep_kernel(
    const float* __restrict__ up, const float* __restrict__ dn,
    const float* __restrict__ wedge,
    const float* __restrict__ w1, const float* __restrict__ w2,
    const float* __restrict__ elec,
    short* __restrict__ w1f, short* __restrict__ w2f,
    short* __restrict__ elecb, short* __restrict__ Tf)
{
    const int idx = (blockIdx.x << 8) + threadIdx.x;   // 0..524287

    if (idx < 65536) {
        { // W1/W2 -> B-frag bf16 (65536 each)
            const int b  = idx & 7;
            const int l  = (idx >> 3) & 63;
            const int q  = (idx >> 9) & 7;
            const int nt = idx >> 12;
            const int j  = (q << 5) + ((l >> 4) << 3) + b;
            const int d  = (nt << 4) + (l & 15);
            w1f[idx] = f2bf(w1[j * DIM + d]);
            w2f[idx] = f2bf(w2[j * DIM + d]);
        }
        { // elec -> row-major bf16, 4 elems/thread
            const f32x4 v = *(const f32x4*)(elec + (idx << 2));
            bf16x4 o;
            o[0] = f2bf(v[0]); o[1] = f2bf(v[1]);
            o[2] = f2bf(v[2]); o[3] = f2bf(v[3]);
            *(bf16x4*)(elecb + (idx << 2)) = o;
        }
    }

    { // T fragments: 2 spins x 262144 threads x 8 elements
        const int s   = idx >> 18;             // 0 = up, 1 = down
        const int rem = idx & 262143;
        const int kt  = rem >> 10;             // nucleus 0..255
        const int dt  = (rem >> 6) & 15;
        const int l   = rem & 63;
        const int d   = (dt << 4) + (l & 15);
        const int jb  = (l >> 4) << 3;         // j base
        const float* __restrict__ inp = s ? dn : up;
        const float iv = inp[kt * DIM + d];
        const float* __restrict__ wcol = wedge + d;
        bf16x8 o;
        #pragma unroll
        for (int b = 0; b < 8; ++b)
            o[b] = f2bf(iv * wcol[(jb + b) * DIM]);
        *(bf16x8*)(Tf + ((size_t)s << 21) + ((size_t)rem << 3)) = o;
    }
}

// ---------------------------------------------------------------------------
// K1 edge_gemm v4: BARRIER-FREE (out_kernel's structure).
// 512 blocks x 512 threads; block = (kp = bid&15, rt = bid>>4 -> 32 rows).
// Each wave loads its own A-frags straight from global (8-way block reuse
// served by L1; per-lane row = rb + 16*rr + c), B-frags from L2-resident Tf.
// No LDS, no __syncthreads -> waves pipeline freely.
// ---------------------------------------------------------------------------
__global__ __launch_bounds__(512) void edge_gemm(
    const float* __restrict__ eemb,
    const short* __restrict__ Tf,
    float* __restrict__ P)             // [16][1024][256] f32 partials
{
    const int tid  = threadIdx.x;
    const int w    = tid >> 6;          // 0..7
    const int lane = tid & 63;
    const int g    = lane >> 4;
    const int c    = lane & 15;
    const int kp   = blockIdx.x & 15;   // K-part (XCD = kp % 8)
    const int rt   = blockIdx.x >> 4;   // row-tile 0..31
    const int rb   = rt << 5;           // 32 rows
    const int kb   = kp << 9;           // K-chunk base (512 per part)

    const short* __restrict__ Tb = Tf + ((rb < N_UP) ? 0 : (1 << 21));

    // per-lane A bases: row = rb + 16*rr + c, k = kb + sub*128 + q*32 + g*8
    const float* __restrict__ Arow0 = eemb + (size_t)(rb + c) * KTOT + kb + (g << 3);
    const float* __restrict__ Arow1 = Arow0 + (size_t)16 * KTOT;

    f32x4 acc[2][2] = {{{0.f,0.f,0.f,0.f},{0.f,0.f,0.f,0.f}},
                       {{0.f,0.f,0.f,0.f},{0.f,0.f,0.f,0.f}}};

    #pragma unroll
    for (int sub = 0; sub < 4; ++sub) {
        // A fragments (per-wave, direct from global; cvt f32->bf16)
        bf16x8 a[2][4];
        #pragma unroll
        for (int rr = 0; rr < 2; ++rr) {
            const float* base = (rr ? Arow1 : Arow0) + (sub << 7);
            #pragma unroll
            for (int q = 0; q < 4; ++q) {
                const f32x4 lo = *(const f32x4*)(base + (q << 5));
                const f32x4 hi = *(const f32x4*)(base + (q << 5) + 4);
                union { bf16x8 v; short s[8]; } f;
                f.s[0] = f2bf(lo[0]); f.s[1] = f2bf(lo[1]);
                f.s[2] = f2bf(lo[2]); f.s[3] = f2bf(lo[3]);
                f.s[4] = f2bf(hi[0]); f.s[5] = f2bf(hi[1]);
                f.s[6] = f2bf(hi[2]); f.s[7] = f2bf(hi[3]);
                a[rr][q] = f.v;
            }
        }
        // B fragments (this wave's two col-tiles)
        bf16x8 b[8];
        #pragma unroll
        for (int t = 0; t < 2; ++t) {
            const int ct = (w << 1) + t;
            #pragma unroll
            for (int q = 0; q < 4; ++q) {
                const int ktg = (kp << 4) + (sub << 2) + q;
                b[(t << 2) + q] = *(const bf16x8*)(
                    Tb + (((((ktg << 4) + ct) << 6) + lane) << 3));
            }
        }
        // 16 MFMAs (4 independent chains)
        #pragma unroll
        for (int q = 0; q < 4; ++q) {
            acc[0][0] = __builtin_amdgcn_mfma_f32_16x16x32_bf16(a[0][q], b[q],     acc[0][0], 0, 0, 0);
            acc[0][1] = __builtin_amdgcn_mfma_f32_16x16x32_bf16(a[0][q], b[4 + q], acc[0][1], 0, 0, 0);
            acc[1][0] = __builtin_amdgcn_mfma_f32_16x16x32_bf16(a[1][q], b[q],     acc[1][0], 0, 0, 0);
            acc[1][1] = __builtin_amdgcn_mfma_f32_16x16x32_bf16(a[1][q], b[4 + q], acc[1][1], 0, 0, 0);
        }
    }

    // epilogue: write kp-partial (C-frag: row = 4g+j, col = c)
    float* __restrict__ Pp = P + ((size_t)kp << 18);
    #pragma unroll
    for (int rr = 0; rr < 2; ++rr)
        #pragma unroll
        for (int t = 0; t < 2; ++t) {
            const int ct = (w << 1) + t;
            #pragma unroll
            for (int j = 0; j < 4; ++j) {
                const int row = rb + (rr << 4) + (g << 2) + j;
                Pp[(row << 8) + (ct << 4) + c] = acc[rr][t][j];
            }
        }
}

// ---------------------------------------------------------------------------
// K2 reduce: agg = s1 * sum_kp P[kp]   (coalesced f32x4, 16 partials)
// ---------------------------------------------------------------------------
__global__ __launch_bounds__(256) void reduce_kernel(
    const float* __restrict__ P,
    const float* __restrict__ s1p,
    float* __restrict__ agg)
{
    const int idx = (blockIdx.x << 8) + threadIdx.x;    // 0..65535
    const float s1 = *s1p;
    f32x4 s = {0.f, 0.f, 0.f, 0.f};
    #pragma unroll
    for (int kp = 0; kp < NKP; ++kp) {
        const f32x4 v = *(const f32x4*)(P + ((size_t)kp << 18) + (idx << 2));
        s[0] += v[0]; s[1] += v[1]; s[2] += v[2]; s[3] += v[3];
    }
    s[0] *= s1; s[1] *= s1; s[2] *= s1; s[3] *= s1;
    *(f32x4*)(agg + (idx << 2)) = s;
}

// ---------------------------------------------------------------------------
// K3 out (R15 body, unchanged)
// ---------------------------------------------------------------------------
__global__ __launch_bounds__(512) void out_kernel(
    const short* __restrict__ elecb,
    const short* __restrict__ w1f, const short* __restrict__ w2f,
    const float* __restrict__ elec, const float* __restrict__ agg,
    const float* __restrict__ norm,
    const float* __restrict__ b1, const float* __restrict__ b2,
    const float* __restrict__ s2p,
    float* __restrict__ outp)
{
    __shared__ short h_s[16][264];      // +8 pad -> 2-way banks (free)

    const int tid  = threadIdx.x;
    const int w    = tid >> 6;          // 0..7
    const int lane = tid & 63;
    const int g    = lane >> 4;
    const int c    = lane & 15;
    const int mt   = blockIdx.x >> 2;   // row-tile 0..63
    const int qd   = blockIdx.x & 3;    // quadrant 0..3
    const int mb   = mt << 4;           // 16 rows per row-tile

    const short* abase = elecb + ((mb + c) << 8) + (g << 3);
    bf16x8 a[8];
    #pragma unroll
    for (int q = 0; q < 8; ++q) a[q] = *(const bf16x8*)(abase + (q << 5));

    const float s2 = *s2p;

    // ---------------- gemm1 (all 16 col-tiles) ----------------
    #pragma unroll
    for (int t = 0; t < 2; ++t) {
        const int ct = (w << 1) + t;
        const short* bb = w1f + (ct << 12) + (lane << 3);
        bf16x8 b[8];
        #pragma unroll
        for (int q = 0; q < 8; ++q) b[q] = *(const bf16x8*)(bb + (q << 9));
        f32x4 acc = {0.f, 0.f, 0.f, 0.f};
        #pragma unroll
        for (int q = 0; q < 8; ++q)
            acc = __builtin_amdgcn_mfma_f32_16x16x32_bf16(a[q], b[q], acc, 0, 0, 0);

        const int n  = (ct << 4) + c;
        const float bv = b1[n];
        #pragma unroll
        for (int r = 0; r < 4; ++r) {
            const int mr = (g << 2) + r;            // 0..15 (C-frag row)
            const int m  = mb + mr;
            const float y = (acc[r] + bv + agg[(m << 8) + n] * norm[m]) * s2;
            const float sig = 1.f / (1.f + __expf(-y));
            h_s[mr][n] = f2bf(GAIN_F * y * sig);
        }
    }
    __syncthreads();

    // ---------------- gemm2 (this block's quadrant; waves 0..3) -------
    if (w < 4) {
        bf16x8 a2[8];                               // row = c, k = q*32+g*8+b
        #pragma unroll
        for (int q = 0; q < 8; ++q)
            a2[q] = *(const bf16x8*)(&h_s[c][(q << 5) + (g << 3)]);

        const int ct = (qd << 2) + w;               // col-tile 0..15, unique
        const short* bb = w2f + (ct << 12) + (lane << 3);
        bf16x8 b[8];
        #pragma unroll
        for (int q = 0; q < 8; ++q) b[q] = *(const bf16x8*)(bb + (q << 9));
        f32x4 acc = {0.f, 0.f, 0.f, 0.f};
        #pragma unroll
        for (int q = 0; q < 8; ++q)
            acc = __builtin_amdgcn_mfma_f32_16x16x32_bf16(a2[q], b[q], acc, 0, 0, 0);

        const int n  = (ct << 4) + c;
        const float bv = b2[n];
        #pragma unroll
        for (int r = 0; r < 4; ++r) {
            const int m = mb + (g << 2) + r;
            const float z = acc[r] + bv;
            const float sig = 1.f / (1.f + __expf(-z));
            const float o = GAIN_F * z * sig;
            outp[(m << 8) + n] = (elec[(m << 8) + n] + o) * INV_SQRT2_F;
        }
    }
}

// ---------------------------------------------------------------------------
extern "C" void kernel_launch(void* const* d_in, const int* in_sizes, int n_in,
                              void* d_out, int out_size, void* d_ws, size_t ws_size,
                              hipStream_t stream)
{
    const float* elec  = (const float*)d_in[0];
    const float* up    = (const float*)d_in[1];
    const float* dn    = (const float*)d_in[2];
    const float* eemb  = (const float*)d_in[3];
    // d_in[4] = contr: init-time only, unused at runtime
    const float* norm  = (const float*)d_in[5];
    const float* W1    = (const float*)d_in[6];
    const float* b1    = (const float*)d_in[7];
    const float* Wedge = (const float*)d_in[8];
    const float* W2    = (const float*)d_in[9];
    const float* b2    = (const float*)d_in[10];
    const float* s1    = (const float*)d_in[11];
    const float* s2    = (const float*)d_in[12];

    // ws layout (shorts): w1f 65536 | w2f 65536 | elecb 262144 |
    //   Tf 4194304 | P f32 16x262144 (16 MB) | agg f32 262144 (1 MB)
    short* sbase = (short*)d_ws;
    short* w1f   = sbase;
    short* w2f   = sbase + 65536;
    short* elecb = sbase + 131072;
    short* Tf    = sbase + 393216;
    float* P     = (float*)(sbase + 393216 + 4194304);
    float* agg   = P + (size_t)NKP * 262144;

    prep_kernel  <<<2048, 256, 0, stream>>>(up, dn, Wedge, W1, W2, elec,
                                            w1f, w2f, elecb, Tf);
    edge_gemm    <<<512, 512, 0, stream>>>(eemb, Tf, P);
    reduce_kernel<<<256, 256, 0, stream>>>(P, s1, agg);
    out_kernel   <<<256, 512, 0, stream>>>(elecb, w1f, w2f, elec, agg, norm,
                                           b1, b2, s2, (float*)d_out);
}

// Round 17
// 30.914 us; speedup vs baseline: 1.7864x; 1.7864x over previous
//
#include <hip/hip_runtime.h>
#include <hip/hip_bf16.h>

// Sizes fixed by setup_inputs()
#define N_EL   1024
#define N_UP   512
#define NNUC   256
#define DIM    256
#define EDIM   32
#define KTOT   8192              // NNUC * EDIM, GEMM K dimension
#define NKP    8                 // K-partitions (K=1024 each) — R12's proven split

#define GAIN_F      1.7872135f          // 1/std(silu(N(0,1))), analytic
#define INV_SQRT2_F 0.7071067811865476f

typedef __attribute__((ext_vector_type(8))) short bf16x8;
typedef __attribute__((ext_vector_type(4))) short bf16x4;
typedef __attribute__((ext_vector_type(4))) float f32x4;

__device__ __forceinline__ short f2bf(float x) {
    union { __hip_bfloat16 h; short s; } u;
    u.h = __float2bfloat16(x);     // compiler pk-fuses pairs (v_cvt_pk_bf16_f32)
    return u.s;
}

// ---------------------------------------------------------------------------
// K0 prep (R15 body, unchanged)
// ---------------------------------------------------------------------------
__global__ __launch_bounds__(256) void prep_kernel(
    const float* __restrict__ up, const float* __restrict__ dn,
    const float* __restrict__ wedge,
    const float* __restrict__ w1, const float* __restrict__ w2,
    const float* __restrict__ elec,
    short* __restrict__ w1f, short* __restrict__ w2f,
    short* __restrict__ elecb, short* __restrict__ Tf)
{
    const int idx = (blockIdx.x << 8) + threadIdx.x;   // 0..524287

    if (idx < 65536) {
        { // W1/W2 -> B-frag bf16 (65536 each)
            const int b  = idx & 7;
            const int l  = (idx >> 3) & 63;
            const int q  = (idx >> 9) & 7;
            const int nt = idx >> 12;
            const int j  = (q << 5) + ((l >> 4) << 3) + b;
            const int d  = (nt << 4) + (l & 15);
            w1f[idx] = f2bf(w1[j * DIM + d]);
            w2f[idx] = f2bf(w2[j * DIM + d]);
        }
        { // elec -> row-major bf16, 4 elems/thread
            const f32x4 v = *(const f32x4*)(elec + (idx << 2));
            bf16x4 o;
            o[0] = f2bf(v[0]); o[1] = f2bf(v[1]);
            o[2] = f2bf(v[2]); o[3] = f2bf(v[3]);
            *(bf16x4*)(elecb + (idx << 2)) = o;
        }
    }

    { // T fragments: 2 spins x 262144 threads x 8 elements
        const int s   = idx >> 18;             // 0 = up, 1 = down
        const int rem = idx & 262143;
        const int kt  = rem >> 10;             // nucleus 0..255
        const int dt  = (rem >> 6) & 15;
        const int l   = rem & 63;
        const int d   = (dt << 4) + (l & 15);
        const int jb  = (l >> 4) << 3;         // j base
        const float* __restrict__ inp = s ? dn : up;
        const float iv = inp[kt * DIM + d];
        const float* __restrict__ wcol = wedge + d;
        bf16x8 o;
        #pragma unroll
        for (int b = 0; b < 8; ++b)
            o[b] = f2bf(iv * wcol[(jb + b) * DIM]);
        *(bf16x8*)(Tf + ((size_t)s << 21) + ((size_t)rem << 3)) = o;
    }
}

// ---------------------------------------------------------------------------
// K1 edge_gemm: R12's v2 VERBATIM (directly measured 10.7 us warm in R13).
// 256 blocks x 512 threads; block = (kp = bid&7 XCD-affine K-part,
// rt = bid>>3 -> M=32 rows). 8 subs of K=128, LDS-staged A (forces VGPR~112,
// loads in flight), B per-wave in regs, dbuf.
// ---------------------------------------------------------------------------
__global__ __launch_bounds__(512) void edge_gemm(
    const float* __restrict__ eemb,
    const short* __restrict__ Tf,
    float* __restrict__ P)             // [8][1024][256] f32 partials
{
    __shared__ short A_lds[2][4096];   // [buf][frag(8)*lane(64)*8] = 8 KB/buf

    const int tid  = threadIdx.x;
    const int w    = tid >> 6;          // 0..7
    const int lane = tid & 63;
    const int g    = lane >> 4;
    const int c    = lane & 15;
    const int kp   = blockIdx.x & 7;    // K-part (XCD round-robin)
    const int rt   = blockIdx.x >> 3;   // row-tile 0..31
    const int rb   = rt << 5;           // 32 rows
    const int kb   = kp << 10;          // K-chunk base (1024 per part)

    const short* __restrict__ Tb = Tf + ((rb < N_UP) ? 0 : (1 << 21));

    const int f  = w;                   // staging frag = wave id
    const int r_ = f >> 2;
    const int q_ = f & 3;
    const float* __restrict__ Asrc = eemb
        + (size_t)(rb + (r_ << 4) + c) * KTOT
        + kb + (q_ << 5) + (g << 3);

    f32x4 s_lo, s_hi;
    bf16x8 bA[8], bB[8];

    auto STAGE_LOAD = [&](int sub) {
        const float* p = Asrc + (sub << 7);
        s_lo = *(const f32x4*)p;
        s_hi = *(const f32x4*)(p + 4);
    };
    auto STAGE_WRITE = [&](int buf) {
        union { bf16x8 v; short s[8]; } o;
        o.s[0] = f2bf(s_lo[0]); o.s[1] = f2bf(s_lo[1]);
        o.s[2] = f2bf(s_lo[2]); o.s[3] = f2bf(s_lo[3]);
        o.s[4] = f2bf(s_hi[0]); o.s[5] = f2bf(s_hi[1]);
        o.s[6] = f2bf(s_hi[2]); o.s[7] = f2bf(s_hi[3]);
        *(bf16x8*)(&A_lds[buf][(f << 9) + (lane << 3)]) = o.v;
    };
    auto LOADB = [&](int sub, bf16x8 (&bd)[8]) {
        #pragma unroll
        for (int t = 0; t < 2; ++t) {
            const int ct = (w << 1) + t;
            #pragma unroll
            for (int q = 0; q < 4; ++q) {
                const int ktg = (kp << 5) + (sub << 2) + q;
                bd[(t << 2) + q] = *(const bf16x8*)(
                    Tb + (((((ktg << 4) + ct) << 6) + lane) << 3));
            }
        }
    };

    f32x4 acc[2][2] = {{{0.f,0.f,0.f,0.f},{0.f,0.f,0.f,0.f}},
                       {{0.f,0.f,0.f,0.f},{0.f,0.f,0.f,0.f}}};

    auto COMPUTE = [&](int buf, bf16x8 (&bc)[8]) {
        bf16x8 a[2][4];
        #pragma unroll
        for (int rr = 0; rr < 2; ++rr)
            #pragma unroll
            for (int q = 0; q < 4; ++q)
                a[rr][q] = *(const bf16x8*)(
                    &A_lds[buf][((((rr << 2) + q)) << 9) + (lane << 3)]);
        #pragma unroll
        for (int q = 0; q < 4; ++q) {
            acc[0][0] = __builtin_amdgcn_mfma_f32_16x16x32_bf16(a[0][q], bc[q],     acc[0][0], 0, 0, 0);
            acc[0][1] = __builtin_amdgcn_mfma_f32_16x16x32_bf16(a[0][q], bc[4 + q], acc[0][1], 0, 0, 0);
            acc[1][0] = __builtin_amdgcn_mfma_f32_16x16x32_bf16(a[1][q], bc[q],     acc[1][0], 0, 0, 0);
            acc[1][1] = __builtin_amdgcn_mfma_f32_16x16x32_bf16(a[1][q], bc[4 + q], acc[1][1], 0, 0, 0);
        }
    };

    // prologue
    STAGE_LOAD(0);
    LOADB(0, bA);
    STAGE_WRITE(0);
    __syncthreads();

    #pragma unroll
    for (int sub = 0; sub < 8; ++sub) {
        if ((sub & 1) == 0) {
            if (sub < 7) { STAGE_LOAD(sub + 1); LOADB(sub + 1, bB); }
            COMPUTE(0, bA);
        } else {
            if (sub < 7) { STAGE_LOAD(sub + 1); LOADB(sub + 1, bA); }
            COMPUTE(1, bB);
        }
        if (sub < 7) STAGE_WRITE((sub & 1) ^ 1);
        __syncthreads();
    }

    // epilogue: write kp-partial (C-frag: row = 4g+j, col = c)
    float* __restrict__ Pp = P + ((size_t)kp << 18);
    #pragma unroll
    for (int rr = 0; rr < 2; ++rr)
        #pragma unroll
        for (int t = 0; t < 2; ++t) {
            const int ct = (w << 1) + t;
            #pragma unroll
            for (int j = 0; j < 4; ++j) {
                const int row = rb + (rr << 4) + (g << 2) + j;
                Pp[(row << 8) + (ct << 4) + c] = acc[rr][t][j];
            }
        }
}

// ---------------------------------------------------------------------------
// K2 reduce: agg = s1 * sum_kp P[kp]   (coalesced f32x4, 8 partials)
// ---------------------------------------------------------------------------
__global__ __launch_bounds__(256) void reduce_kernel(
    const float* __restrict__ P,
    const float* __restrict__ s1p,
    float* __restrict__ agg)
{
    const int idx = (blockIdx.x << 8) + threadIdx.x;    // 0..65535
    const float s1 = *s1p;
    f32x4 s = {0.f, 0.f, 0.f, 0.f};
    #pragma unroll
    for (int kp = 0; kp < NKP; ++kp) {
        const f32x4 v = *(const f32x4*)(P + ((size_t)kp << 18) + (idx << 2));
        s[0] += v[0]; s[1] += v[1]; s[2] += v[2]; s[3] += v[3];
    }
    s[0] *= s1; s[1] *= s1; s[2] *= s1; s[3] *= s1;
    *(f32x4*)(agg + (idx << 2)) = s;
}

// ---------------------------------------------------------------------------
// K3 out (R15 body, unchanged)
// ---------------------------------------------------------------------------
__global__ __launch_bounds__(512) void out_kernel(
    const short* __restrict__ elecb,
    const short* __restrict__ w1f, const short* __restrict__ w2f,
    const float* __restrict__ elec, const float* __restrict__ agg,
    const float* __restrict__ norm,
    const float* __restrict__ b1, const float* __restrict__ b2,
    const float* __restrict__ s2p,
    float* __restrict__ outp)
{
    __shared__ short h_s[16][264];      // +8 pad -> 2-way banks (free)

    const int tid  = threadIdx.x;
    const int w    = tid >> 6;          // 0..7
    const int lane = tid & 63;
    const int g    = lane >> 4;
    const int c    = lane & 15;
    const int mt   = blockIdx.x >> 2;   // row-tile 0..63
    const int qd   = blockIdx.x & 3;    // quadrant 0..3
    const int mb   = mt << 4;           // 16 rows per row-tile

    const short* abase = elecb + ((mb + c) << 8) + (g << 3);
    bf16x8 a[8];
    #pragma unroll
    for (int q = 0; q < 8; ++q) a[q] = *(const bf16x8*)(abase + (q << 5));

    const float s2 = *s2p;

    // ---------------- gemm1 (all 16 col-tiles) ----------------
    #pragma unroll
    for (int t = 0; t < 2; ++t) {
        const int ct = (w << 1) + t;
        const short* bb = w1f + (ct << 12) + (lane << 3);
        bf16x8 b[8];
        #pragma unroll
        for (int q = 0; q < 8; ++q) b[q] = *(const bf16x8*)(bb + (q << 9));
        f32x4 acc = {0.f, 0.f, 0.f, 0.f};
        #pragma unroll
        for (int q = 0; q < 8; ++q)
            acc = __builtin_amdgcn_mfma_f32_16x16x32_bf16(a[q], b[q], acc, 0, 0, 0);

        const int n  = (ct << 4) + c;
        const float bv = b1[n];
        #pragma unroll
        for (int r = 0; r < 4; ++r) {
            const int mr = (g << 2) + r;            // 0..15 (C-frag row)
            const int m  = mb + mr;
            const float y = (acc[r] + bv + agg[(m << 8) + n] * norm[m]) * s2;
            const float sig = 1.f / (1.f + __expf(-y));
            h_s[mr][n] = f2bf(GAIN_F * y * sig);
        }
    }
    __syncthreads();

    // ---------------- gemm2 (this block's quadrant; waves 0..3) -------
    if (w < 4) {
        bf16x8 a2[8];                               // row = c, k = q*32+g*8+b
        #pragma unroll
        for (int q = 0; q < 8; ++q)
            a2[q] = *(const bf16x8*)(&h_s[c][(q << 5) + (g << 3)]);

        const int ct = (qd << 2) + w;               // col-tile 0..15, unique
        const short* bb = w2f + (ct << 12) + (lane << 3);
        bf16x8 b[8];
        #pragma unroll
        for (int q = 0; q < 8; ++q) b[q] = *(const bf16x8*)(bb + (q << 9));
        f32x4 acc = {0.f, 0.f, 0.f, 0.f};
        #pragma unroll
        for (int q = 0; q < 8; ++q)
            acc = __builtin_amdgcn_mfma_f32_16x16x32_bf16(a2[q], b[q], acc, 0, 0, 0);

        const int n  = (ct << 4) + c;
        const float bv = b2[n];
        #pragma unroll
        for (int r = 0; r < 4; ++r) {
            const int m = mb + (g << 2) + r;
            const float z = acc[r] + bv;
            const float sig = 1.f / (1.f + __expf(-z));
            const float o = GAIN_F * z * sig;
            outp[(m << 8) + n] = (elec[(m << 8) + n] + o) * INV_SQRT2_F;
        }
    }
}

// ---------------------------------------------------------------------------
extern "C" void kernel_launch(void* const* d_in, const int* in_sizes, int n_in,
                              void* d_out, int out_size, void* d_ws, size_t ws_size,
                              hipStream_t stream)
{
    const float* elec  = (const float*)d_in[0];
    const float* up    = (const float*)d_in[1];
    const float* dn    = (const float*)d_in[2];
    const float* eemb  = (const float*)d_in[3];
    // d_in[4] = contr: init-time only, unused at runtime
    const float* norm  = (const float*)d_in[5];
    const float* W1    = (const float*)d_in[6];
    const float* b1    = (const float*)d_in[7];
    const float* Wedge = (const float*)d_in[8];
    const float* W2    = (const float*)d_in[9];
    const float* b2    = (const float*)d_in[10];
    const float* s1    = (const float*)d_in[11];
    const float* s2    = (const float*)d_in[12];

    // ws layout (shorts): w1f 65536 | w2f 65536 | elecb 262144 |
    //   Tf 4194304 | P f32 8x262144 (8 MB) | agg f32 262144 (1 MB)
    short* sbase = (short*)d_ws;
    short* w1f   = sbase;
    short* w2f   = sbase + 65536;
    short* elecb = sbase + 131072;
    short* Tf    = sbase + 393216;
    float* P     = (float*)(sbase + 393216 + 4194304);
    float* agg   = P + (size_t)NKP * 262144;

    prep_kernel  <<<2048, 256, 0, stream>>>(up, dn, Wedge, W1, W2, elec,
                                            w1f, w2f, elecb, Tf);
    edge_gemm    <<<256, 512, 0, stream>>>(eemb, Tf, P);
    reduce_kernel<<<256, 256, 0, stream>>>(P, s1, agg);
    out_kernel   <<<256, 512, 0, stream>>>(elecb, w1f, w2f, elec, agg, norm,
                                           b1, b2, s2, (float*)d_out);
}